// Round 1
// baseline (632.651 us; speedup 1.0000x reference)
//
#include <hip/hip_runtime.h>
#include <math.h>

#define BB    4
#define SEQ   1024
#define DIMV  512
#define TD    1536
#define NH    8
#define DH    128
#define MROWS (BB*SEQ)

// ---------------- Kernel 1: QKV GEMM (f32) ----------------
// C = In(4096x512) @ W(512x1536), scattered into q/k/v head-layout ws buffers.
#define GBM 128
#define GBN 64
#define GBK 16
#define ASTR 140   // padded LDS stride for A-tile (bank-conflict-free, 16B aligned)
#define BSTR 68    // padded LDS stride for B-tile

__global__ __launch_bounds__(256) void qkv_gemm(
    const float* __restrict__ X, const float* __restrict__ A,
    const float* __restrict__ Wx, const float* __restrict__ Wa,
    float* __restrict__ wsq, float* __restrict__ wsk, float* __restrict__ wsv)
{
    __shared__ float As[GBK*ASTR];
    __shared__ float Bs[GBK*BSTR];
    const int mat = blockIdx.z;
    const float* In = mat ? A : X;
    const float* W  = mat ? Wa : Wx;
    const int bm = blockIdx.x * GBM;
    const int bn = blockIdx.y * GBN;
    const int tid = threadIdx.x;
    const int tx = tid & 15;
    const int ty = tid >> 4;

    float c[8][4];
    #pragma unroll
    for (int i=0;i<8;++i)
        #pragma unroll
        for (int j=0;j<4;++j) c[i][j]=0.f;

    const int rl = tid >> 2;          // 0..63  (A-tile row, 2 passes)
    const int kk = (tid & 3) << 2;    // 0,4,8,12
    const int wk = tid >> 4;          // 0..15  (W-tile row)
    const int wn = (tid & 15) << 2;   // 0..60  (W-tile col)

    for (int k0=0; k0<DIMV; k0+=GBK){
        #pragma unroll
        for (int h=0; h<2; ++h){
            int row = rl + h*64;
            float4 xv = *(const float4*)(In + (size_t)(bm+row)*DIMV + k0 + kk);
            As[(kk+0)*ASTR + row] = xv.x;
            As[(kk+1)*ASTR + row] = xv.y;
            As[(kk+2)*ASTR + row] = xv.z;
            As[(kk+3)*ASTR + row] = xv.w;
        }
        {
            float4 wv = *(const float4*)(W + (size_t)(k0+wk)*TD + bn + wn);
            *(float4*)(Bs + wk*BSTR + wn) = wv;
        }
        __syncthreads();
        #pragma unroll
        for (int k=0;k<GBK;++k){
            float4 a0 = *(const float4*)(As + k*ASTR + ty*8);
            float4 a1 = *(const float4*)(As + k*ASTR + ty*8 + 4);
            float4 b0 = *(const float4*)(Bs + k*BSTR + tx*4);
            float a[8] = {a0.x,a0.y,a0.z,a0.w,a1.x,a1.y,a1.z,a1.w};
            float bv[4] = {b0.x,b0.y,b0.z,b0.w};
            #pragma unroll
            for (int i=0;i<8;++i)
                #pragma unroll
                for (int j=0;j<4;++j)
                    c[i][j] = fmaf(a[i], bv[j], c[i][j]);
        }
        __syncthreads();
    }

    // scatter into (B,H,SEQ,DH) head layout
    const int cbase = bn + tx*4;
    const int tensor = cbase >> 9;          // 0=q, 1=k, 2=v
    const int wc = cbase & 511;
    const int h = (mat ? 4 : 0) + (wc >> 7);
    const int d = wc & 127;
    float* base = (tensor==0) ? wsq : (tensor==1) ? wsk : wsv;
    #pragma unroll
    for (int i=0;i<8;++i){
        int m = bm + ty*8 + i;
        int b_ = m >> 10;
        int n_ = m & 1023;
        float* dst = base + (((size_t)(b_*NH + h)*SEQ + n_)*DH + d);
        *(float4*)dst = make_float4(c[i][0],c[i][1],c[i][2],c[i][3]);
    }
}

// ---------------- Kernel 2: LayerNorm + RoPE (in place) ----------------
// grid (4096, 4): y=0 q_x, 1 k_x, 2 q_a, 3 k_a. 512 threads = the 512 LN dims.
__global__ __launch_bounds__(512) void ln_rope(
    float* __restrict__ wsq, float* __restrict__ wsk,
    const float* __restrict__ g_qx, const float* __restrict__ b_qx,
    const float* __restrict__ g_kx, const float* __restrict__ b_kx,
    const float* __restrict__ g_qa, const float* __restrict__ b_qa,
    const float* __restrict__ g_ka, const float* __restrict__ b_ka)
{
    __shared__ float red[16];
    __shared__ float vn[512];
    const int r = blockIdx.x;
    const int which = blockIdx.y;
    const int b_ = r >> 10;
    const int n_ = r & 1023;
    float* buf = (which & 1) ? wsk : wsq;
    const int h0 = (which >> 1) ? 4 : 0;
    const float* g; const float* bb;
    if (which==0){ g=g_qx; bb=b_qx; }
    else if (which==1){ g=g_kx; bb=b_kx; }
    else if (which==2){ g=g_qa; bb=b_qa; }
    else { g=g_ka; bb=b_ka; }

    const int t = threadIdx.x;
    const int h = h0 + (t >> 7);
    const int d = t & 127;
    const size_t idx = ((size_t)(b_*NH + h)*SEQ + n_)*DH + d;
    float v = buf[idx];
    float s1 = v, s2 = v*v;
    #pragma unroll
    for (int o=32;o>=1;o>>=1){
        s1 += __shfl_down(s1,o);
        s2 += __shfl_down(s2,o);
    }
    const int lane = t & 63, wv = t >> 6;
    if (lane==0){ red[wv]=s1; red[8+wv]=s2; }
    __syncthreads();
    float sum=0.f, sq=0.f;
    #pragma unroll
    for (int w=0;w<8;++w){ sum+=red[w]; sq+=red[8+w]; }
    const float mu = sum * (1.f/512.f);
    const float var = sq * (1.f/512.f) - mu*mu;
    const float rs = rsqrtf(var + 1e-5f);
    const float xn = (v - mu)*rs*g[t] + bb[t];
    vn[t] = xn;
    __syncthreads();
    const float partner = vn[t ^ 64];
    const int dd = d & 63;
    const float fr = (float)dd * (1.f/64.f);
    const float inv = expf(fr * -9.210340371976184f);   // 10000^{-dd/64}
    const float ang = (float)n_ * inv;
    float sn, cs;
    sincosf(ang, &sn, &cs);
    const float rot = (d < 64) ? -partner : partner;
    buf[idx] = xn*cs + rot*sn;
}

// ---------------- Kernel 3: flash attention (f32) ----------------
// grid (16, 32): x = q-tile (64 rows), y = b*H+h. 256 threads.
// LDS exactly 64KB: Q 32K, K 16K (aliased P/alpha/l after S-phase), V 16K.
// All tiles stored float4-swizzled to avoid stride-128 bank conflicts.
#define QB 64
#define KB 32

__global__ __launch_bounds__(256) void attn_fwd(
    const float* __restrict__ q, const float* __restrict__ k,
    const float* __restrict__ v, float* __restrict__ out)
{
    __shared__ float Qs[QB*DH];
    __shared__ float Ks[KB*DH];
    __shared__ float Vs[KB*DH];
    const int bh = blockIdx.y;
    const int q0 = blockIdx.x * QB;
    const size_t off = (size_t)bh * SEQ * DH;
    const float* qp = q + off + (size_t)q0*DH;
    const float* kp = k + off;
    const float* vp = v + off;
    const int tid = threadIdx.x;

    float4* Q4 = (float4*)Qs;
    float4* K4 = (float4*)Ks;
    float4* V4 = (float4*)Vs;

    // stage Q, swizzled by (row>>1)&7
    #pragma unroll
    for (int i=0;i<8;++i){
        int f = tid + i*256;
        int row = f >> 5, fi = f & 31;
        Q4[row*32 + (fi ^ ((row>>1)&7))] = ((const float4*)qp)[f];
    }

    const int srow = (tid >> 3) << 1;   // S-phase: rows srow, srow+1
    const int scol = (tid & 7) << 2;    // S-phase: 4 k-cols
    const int prow = tid >> 2;          // PV: one row
    const int pdf  = (tid & 3) << 3;    // PV: float4-unit base (8 float4 = 32 d)
    float m0r = -1e30f, m1r = -1e30f, l0r = 0.f, l1r = 0.f;
    float acc[32];
    #pragma unroll
    for (int i=0;i<32;++i) acc[i]=0.f;

    float* ps      = Ks;                 // [64][32] P-matrix, aliases dead K
    float* alpha_s = Ks + QB*KB;         // [64]
    float* lfin    = Ks + QB*KB + QB;    // [64]

    const float scale = 0.08838834764831845f;  // 1/sqrt(128)
    const int qrb = srow*32;
    const int qsw = (srow>>1)&7;

    for (int kt=0; kt<SEQ/KB; ++kt){
        __syncthreads();   // previous PV readers done before overwriting K/V
        #pragma unroll
        for (int i=0;i<4;++i){
            int f = tid + i*256;
            int row = f >> 5, fi = f & 31;
            int sw = (row>>2)&7;
            K4[row*32 + (fi ^ sw)] = ((const float4*)(kp + (size_t)kt*KB*DH))[f];
            V4[row*32 + (fi ^ sw)] = ((const float4*)(vp + (size_t)kt*KB*DH))[f];
        }
        __syncthreads();

        // ---- S = Q K^T (2 rows x 4 cols per thread) ----
        float s[2][4] = {{0,0,0,0},{0,0,0,0}};
        #pragma unroll 4
        for (int f=0; f<32; ++f){
            float4 qa = Q4[qrb + (f ^ qsw)];
            float4 qc = Q4[qrb + 32 + (f ^ qsw)];
            #pragma unroll
            for (int j=0;j<4;++j){
                int kc = scol + j;
                float4 kv = K4[kc*32 + (f ^ ((kc>>2)&7))];
                s[0][j] += qa.x*kv.x + qa.y*kv.y + qa.z*kv.z + qa.w*kv.w;
                s[1][j] += qc.x*kv.x + qc.y*kv.y + qc.z*kv.z + qc.w*kv.w;
            }
        }

        // ---- online softmax (8-lane row groups) ----
        float mt0 = -1e30f, mt1 = -1e30f;
        #pragma unroll
        for (int j=0;j<4;++j){
            s[0][j] *= scale; s[1][j] *= scale;
            mt0 = fmaxf(mt0, s[0][j]); mt1 = fmaxf(mt1, s[1][j]);
        }
        #pragma unroll
        for (int o=1;o<8;o<<=1){
            mt0 = fmaxf(mt0, __shfl_xor(mt0,o));
            mt1 = fmaxf(mt1, __shfl_xor(mt1,o));
        }
        const float mn0 = fmaxf(m0r, mt0), mn1 = fmaxf(m1r, mt1);
        const float a0 = __expf(m0r - mn0), a1 = __expf(m1r - mn1);
        float p[2][4]; float su0=0.f, su1=0.f;
        #pragma unroll
        for (int j=0;j<4;++j){
            p[0][j] = __expf(s[0][j] - mn0);
            p[1][j] = __expf(s[1][j] - mn1);
            su0 += p[0][j]; su1 += p[1][j];
        }
        #pragma unroll
        for (int o=1;o<8;o<<=1){ su0 += __shfl_xor(su0,o); su1 += __shfl_xor(su1,o); }
        l0r = l0r*a0 + su0;  l1r = l1r*a1 + su1;
        m0r = mn0; m1r = mn1;

        __syncthreads();   // all K-tile reads done; safe to overwrite with P
        #pragma unroll
        for (int j=0;j<4;++j){
            ps[srow*32 + scol + j]     = p[0][j];
            ps[(srow+1)*32 + scol + j] = p[1][j];
        }
        if ((tid & 7)==0){ alpha_s[srow] = a0; alpha_s[srow+1] = a1; }
        __syncthreads();

        // ---- O = alpha*O + P V (1 row x 32 d per thread) ----
        const float al = alpha_s[prow];
        #pragma unroll
        for (int i=0;i<32;++i) acc[i] *= al;
        for (int kc=0;kc<KB;++kc){
            const float pv = ps[prow*32 + kc];
            const int sw = (kc>>2)&7;
            #pragma unroll
            for (int i=0;i<8;++i){
                float4 vv = V4[kc*32 + ((pdf+i) ^ sw)];
                acc[i*4+0] = fmaf(pv, vv.x, acc[i*4+0]);
                acc[i*4+1] = fmaf(pv, vv.y, acc[i*4+1]);
                acc[i*4+2] = fmaf(pv, vv.z, acc[i*4+2]);
                acc[i*4+3] = fmaf(pv, vv.w, acc[i*4+3]);
            }
        }
    }

    __syncthreads();
    if ((tid & 7)==0){ lfin[srow] = l0r; lfin[srow+1] = l1r; }
    __syncthreads();
    const float invl = 1.0f / lfin[prow];

    const int b_ = bh >> 3, h_ = bh & 7;
    const int n_ = q0 + prow;
    float* op = out + ((size_t)(b_*SEQ + n_)*(NH*DH)) + h_*DH + pdf*4;
    #pragma unroll
    for (int i=0;i<8;++i){
        *(float4*)(op + i*4) = make_float4(acc[i*4+0]*invl, acc[i*4+1]*invl,
                                           acc[i*4+2]*invl, acc[i*4+3]*invl);
    }
}

extern "C" void kernel_launch(void* const* d_in, const int* in_sizes, int n_in,
                              void* d_out, int out_size, void* d_ws, size_t ws_size,
                              hipStream_t stream) {
    const float* x    = (const float*)d_in[0];
    const float* a    = (const float*)d_in[1];
    const float* Wx   = (const float*)d_in[2];
    const float* Wa   = (const float*)d_in[3];
    const float* g_qx = (const float*)d_in[4];
    const float* b_qx = (const float*)d_in[5];
    const float* g_kx = (const float*)d_in[6];
    const float* b_kx = (const float*)d_in[7];
    const float* g_qa = (const float*)d_in[8];
    const float* b_qa = (const float*)d_in[9];
    const float* g_ka = (const float*)d_in[10];
    const float* b_ka = (const float*)d_in[11];
    float* out = (float*)d_out;

    // workspace: q,k,v in (B,H,SEQ,DH) f32 = 16MB each (48MB total)
    float* wsq = (float*)d_ws;
    float* wsk = wsq + (size_t)BB*NH*SEQ*DH;
    float* wsv = wsk + (size_t)BB*NH*SEQ*DH;

    qkv_gemm<<<dim3(MROWS/GBM, TD/GBN, 2), 256, 0, stream>>>(x, a, Wx, Wa, wsq, wsk, wsv);
    ln_rope<<<dim3(MROWS, 4), 512, 0, stream>>>(wsq, wsk,
        g_qx, b_qx, g_kx, b_kx, g_qa, b_qa, g_ka, b_ka);
    attn_fwd<<<dim3(SEQ/QB, BB*NH), 256, 0, stream>>>(wsq, wsk, wsv, out);
}

// Round 2
// 234.413 us; speedup vs baseline: 2.6989x; 2.6989x over previous
//
#include <hip/hip_runtime.h>
#include <math.h>

typedef __attribute__((ext_vector_type(8))) short bf16x8;
typedef __attribute__((ext_vector_type(4))) float f32x4;

#define BB    4
#define SEQ   1024
#define DIMV  512
#define TD    1536
#define NH    8
#define DH    128
#define MROWS (BB*SEQ)

__device__ inline unsigned short f2bf(float x){
    union { float f; unsigned u; } v; v.f = x;
    unsigned r = v.u + 0x7FFF + ((v.u >> 16) & 1);   // RNE
    return (unsigned short)(r >> 16);
}

// ---------------- Kernel 1: QKV GEMM (f32 compute) ----------------
// Q,K -> f32 ws (head layout). V -> bf16 TRANSPOSED [B,H,DH,SEQ] for MFMA PV.
#define GBM 128
#define GBN 64
#define GBK 16
#define ASTR 140
#define BSTR 68

__global__ __launch_bounds__(256) void qkv_gemm(
    const float* __restrict__ X, const float* __restrict__ A,
    const float* __restrict__ Wx, const float* __restrict__ Wa,
    float* __restrict__ wsq, float* __restrict__ wsk,
    unsigned short* __restrict__ Vt)
{
    __shared__ float As[GBK*ASTR];
    __shared__ float Bs[GBK*BSTR];
    const int mat = blockIdx.z;
    const float* In = mat ? A : X;
    const float* W  = mat ? Wa : Wx;
    const int bm = blockIdx.x * GBM;
    const int bn = blockIdx.y * GBN;
    const int tid = threadIdx.x;
    const int tx = tid & 15;
    const int ty = tid >> 4;

    float c[8][4];
    #pragma unroll
    for (int i=0;i<8;++i)
        #pragma unroll
        for (int j=0;j<4;++j) c[i][j]=0.f;

    const int rl = tid >> 2;
    const int kk = (tid & 3) << 2;
    const int wk = tid >> 4;
    const int wn = (tid & 15) << 2;

    for (int k0=0; k0<DIMV; k0+=GBK){
        #pragma unroll
        for (int h=0; h<2; ++h){
            int row = rl + h*64;
            float4 xv = *(const float4*)(In + (size_t)(bm+row)*DIMV + k0 + kk);
            As[(kk+0)*ASTR + row] = xv.x;
            As[(kk+1)*ASTR + row] = xv.y;
            As[(kk+2)*ASTR + row] = xv.z;
            As[(kk+3)*ASTR + row] = xv.w;
        }
        {
            float4 wv = *(const float4*)(W + (size_t)(k0+wk)*TD + bn + wn);
            *(float4*)(Bs + wk*BSTR + wn) = wv;
        }
        __syncthreads();
        #pragma unroll
        for (int k=0;k<GBK;++k){
            float4 a0 = *(const float4*)(As + k*ASTR + ty*8);
            float4 a1 = *(const float4*)(As + k*ASTR + ty*8 + 4);
            float4 b0 = *(const float4*)(Bs + k*BSTR + tx*4);
            float a[8] = {a0.x,a0.y,a0.z,a0.w,a1.x,a1.y,a1.z,a1.w};
            float bv[4] = {b0.x,b0.y,b0.z,b0.w};
            #pragma unroll
            for (int i=0;i<8;++i)
                #pragma unroll
                for (int j=0;j<4;++j)
                    c[i][j] = fmaf(a[i], bv[j], c[i][j]);
        }
        __syncthreads();
    }

    const int cbase = bn + tx*4;
    const int tensor = cbase >> 9;          // 0=q, 1=k, 2=v
    const int wc = cbase & 511;
    const int h = (mat ? 4 : 0) + (wc >> 7);
    const int d = wc & 127;

    if (tensor < 2){
        float* base = (tensor==0) ? wsq : wsk;
        #pragma unroll
        for (int i=0;i<8;++i){
            int m = bm + ty*8 + i;
            int b_ = m >> 10;
            int n_ = m & 1023;
            float* dst = base + (((size_t)(b_*NH + h)*SEQ + n_)*DH + d);
            *(float4*)dst = make_float4(c[i][0],c[i][1],c[i][2],c[i][3]);
        }
    } else {
        // V: write bf16 transposed [B,H,DH,SEQ]
        const int b_ = bm >> 10;
        const int n0 = (bm & 1023) + ty*8;
        const size_t vb = (size_t)(b_*NH + h) * DH;
        #pragma unroll
        for (int j=0;j<4;++j){
            bf16x8 pk;
            #pragma unroll
            for (int i=0;i<8;++i) pk[i] = (short)f2bf(c[i][j]);
            *(bf16x8*)(Vt + (vb + d + j)*SEQ + n0) = pk;
        }
    }
}

// ---------------- Kernel 2: LayerNorm + RoPE -> bf16 ----------------
__global__ __launch_bounds__(512) void ln_rope(
    const float* __restrict__ wsq, const float* __restrict__ wsk,
    unsigned short* __restrict__ Qb, unsigned short* __restrict__ Kb,
    const float* __restrict__ g_qx, const float* __restrict__ b_qx,
    const float* __restrict__ g_kx, const float* __restrict__ b_kx,
    const float* __restrict__ g_qa, const float* __restrict__ b_qa,
    const float* __restrict__ g_ka, const float* __restrict__ b_ka)
{
    __shared__ float red[16];
    __shared__ float vn[512];
    const int r = blockIdx.x;
    const int which = blockIdx.y;
    const int b_ = r >> 10;
    const int n_ = r & 1023;
    const float* buf = (which & 1) ? wsk : wsq;
    unsigned short* ob = (which & 1) ? Kb : Qb;
    const int h0 = (which >> 1) ? 4 : 0;
    const float* g; const float* bb;
    if (which==0){ g=g_qx; bb=b_qx; }
    else if (which==1){ g=g_kx; bb=b_kx; }
    else if (which==2){ g=g_qa; bb=b_qa; }
    else { g=g_ka; bb=b_ka; }

    const int t = threadIdx.x;
    const int h = h0 + (t >> 7);
    const int d = t & 127;
    const size_t idx = ((size_t)(b_*NH + h)*SEQ + n_)*DH + d;
    float v = buf[idx];
    float s1 = v, s2 = v*v;
    #pragma unroll
    for (int o=32;o>=1;o>>=1){
        s1 += __shfl_down(s1,o);
        s2 += __shfl_down(s2,o);
    }
    const int lane = t & 63, wv = t >> 6;
    if (lane==0){ red[wv]=s1; red[8+wv]=s2; }
    __syncthreads();
    float sum=0.f, sq=0.f;
    #pragma unroll
    for (int w=0;w<8;++w){ sum+=red[w]; sq+=red[8+w]; }
    const float mu = sum * (1.f/512.f);
    const float var = sq * (1.f/512.f) - mu*mu;
    const float rs = rsqrtf(var + 1e-5f);
    const float xn = (v - mu)*rs*g[t] + bb[t];
    vn[t] = xn;
    __syncthreads();
    const float partner = vn[t ^ 64];
    const int dd = d & 63;
    const float fr = (float)dd * (1.f/64.f);
    const float inv = expf(fr * -9.210340371976184f);
    const float ang = (float)n_ * inv;
    float sn, cs;
    sincosf(ang, &sn, &cs);
    const float rot = (d < 64) ? -partner : partner;
    float val = xn*cs + rot*sn;
    if (!(which & 1)) val *= 0.08838834764831845f;   // fold 1/sqrt(128) into Q
    ob[idx] = f2bf(val);
}

// ---------------- Kernel 3: MFMA flash attention (bf16) ----------------
// 4 waves x 16 q-rows (QB=64), KB=64. K/V^T staged in swizzled LDS.
// P relaid through per-wave swizzled LDS (D-layout -> A-fragment layout).
__global__ __launch_bounds__(256) void attn_mfma(
    const unsigned short* __restrict__ Qb, const unsigned short* __restrict__ Kb,
    const unsigned short* __restrict__ Vt, float* __restrict__ out)
{
    __shared__ __align__(16) unsigned short Ks[64*128];   // 16KB, swizzled
    __shared__ __align__(16) unsigned short Vs[128*64];   // 16KB, V^T, swizzled
    __shared__ __align__(16) unsigned short Ps[4*16*64];  // 8KB, per-wave P

    const int bh = blockIdx.y;
    const int q0 = blockIdx.x * 64;
    const int tid = threadIdx.x;
    const int w  = tid >> 6;
    const int l  = tid & 63;
    const int lg = l >> 4;      // 0..3
    const int ln = l & 15;      // 0..15
    const size_t hoff = (size_t)bh * SEQ * DH;

    // Q fragments: wave's 16 rows, 4 d-chunks of 32 (already scaled by 1/sqrt(128))
    bf16x8 qf[4];
    {
        const unsigned short* qp = Qb + hoff + (size_t)(q0 + w*16 + ln)*DH + lg*8;
        #pragma unroll
        for (int c=0;c<4;++c) qf[c] = *(const bf16x8*)(qp + c*32);
    }

    f32x4 o[8];
    #pragma unroll
    for (int dt=0;dt<8;++dt){ o[dt][0]=0.f; o[dt][1]=0.f; o[dt][2]=0.f; o[dt][3]=0.f; }
    float mrun[4] = {-INFINITY,-INFINITY,-INFINITY,-INFINITY};
    float lrun[4] = {0.f,0.f,0.f,0.f};

    const unsigned short* kg0 = Kb + hoff;
    const unsigned short* vg0 = Vt + hoff;
    unsigned short* Pw = Ps + w*1024;
    const int lnsw = ln & 7;

    for (int kt=0; kt<SEQ/64; ++kt){
        __syncthreads();
        // stage K tile (64 rows x 128 bf16), unit-XOR swizzle: u ^= row&7
        const unsigned short* kg = kg0 + (size_t)kt*64*DH;
        #pragma unroll
        for (int i=0;i<4;++i){
            int f = tid + i*256;
            int r = f >> 4, u = f & 15;
            *(bf16x8*)(Ks + r*128 + ((u ^ (r&7))*8)) = *(const bf16x8*)(kg + r*128 + u*8);
        }
        // stage V^T tile (128 rows x 64 bf16)
        #pragma unroll
        for (int i=0;i<4;++i){
            int f = tid + i*256;
            int dr = f >> 3, u = f & 7;
            *(bf16x8*)(Vs + dr*64 + ((u ^ (dr&7))*8)) =
                *(const bf16x8*)(vg0 + (size_t)dr*SEQ + kt*64 + u*8);
        }
        __syncthreads();

        // ---- S = Q K^T : 4 col-tiles x 4 d-chunks ----
        f32x4 s[4];
        #pragma unroll
        for (int ct=0;ct<4;++ct){ s[ct][0]=0.f; s[ct][1]=0.f; s[ct][2]=0.f; s[ct][3]=0.f; }
        #pragma unroll
        for (int ct=0; ct<4; ++ct){
            const int kr = ct*16 + ln;
            const unsigned short* kb = Ks + kr*128;
            const int sw = kr & 7;
            #pragma unroll
            for (int c=0;c<4;++c){
                bf16x8 kf = *(const bf16x8*)(kb + ((((c<<2)|lg) ^ sw)*8));
                s[ct] = __builtin_amdgcn_mfma_f32_16x16x32_bf16(qf[c], kf, s[ct], 0,0,0);
            }
        }

        // ---- online softmax (rows are lane-local in C/D layout) ----
        float pv[4][4];
        float al[4];
        #pragma unroll
        for (int r=0;r<4;++r){
            float mx = fmaxf(fmaxf(s[0][r], s[1][r]), fmaxf(s[2][r], s[3][r]));
            mx = fmaxf(mx, __shfl_xor(mx,1));
            mx = fmaxf(mx, __shfl_xor(mx,2));
            mx = fmaxf(mx, __shfl_xor(mx,4));
            mx = fmaxf(mx, __shfl_xor(mx,8));
            const float mn = fmaxf(mrun[r], mx);
            const float a  = __expf(mrun[r]-mn);
            float sum = 0.f;
            #pragma unroll
            for (int ct=0;ct<4;++ct){
                float p = __expf(s[ct][r]-mn);
                pv[r][ct] = p; sum += p;
            }
            sum += __shfl_xor(sum,1);
            sum += __shfl_xor(sum,2);
            sum += __shfl_xor(sum,4);
            sum += __shfl_xor(sum,8);
            lrun[r] = lrun[r]*a + sum;
            mrun[r] = mn;
            al[r] = a;
        }

        // rescale O
        #pragma unroll
        for (int dt=0;dt<8;++dt){
            o[dt][0]*=al[0]; o[dt][1]*=al[1]; o[dt][2]*=al[2]; o[dt][3]*=al[3];
        }

        // ---- write P (bf16, swizzled) ----
        #pragma unroll
        for (int r=0;r<4;++r){
            const int m = lg*4 + r;
            unsigned short* pr = Pw + m*64;
            const int sw = m & 7;
            #pragma unroll
            for (int ct=0;ct<4;++ct){
                int col = ct*16 + ln;
                pr[(((col>>3) ^ sw)*8) + (col&7)] = f2bf(pv[r][ct]);
            }
        }

        // ---- O += P V ----
        #pragma unroll
        for (int kc=0;kc<2;++kc){
            bf16x8 pf = *(const bf16x8*)(Pw + ln*64 + ((((kc<<2)|lg) ^ lnsw)*8));
            #pragma unroll
            for (int dt=0;dt<8;++dt){
                const int vr = dt*16 + ln;
                bf16x8 vf = *(const bf16x8*)(Vs + vr*64 + ((((kc<<2)|lg) ^ lnsw)*8));
                o[dt] = __builtin_amdgcn_mfma_f32_16x16x32_bf16(pf, vf, o[dt], 0,0,0);
            }
        }
    }

    // ---- epilogue ----
    const int b_ = bh >> 3, h_ = bh & 7;
    #pragma unroll
    for (int r=0;r<4;++r){
        const float inv = 1.0f / lrun[r];
        const int n_ = q0 + w*16 + lg*4 + r;
        float* op = out + ((size_t)(b_*SEQ) + n_)*1024 + h_*128 + ln;
        #pragma unroll
        for (int dt=0;dt<8;++dt)
            op[dt*16] = o[dt][r] * inv;
    }
}

extern "C" void kernel_launch(void* const* d_in, const int* in_sizes, int n_in,
                              void* d_out, int out_size, void* d_ws, size_t ws_size,
                              hipStream_t stream) {
    const float* x    = (const float*)d_in[0];
    const float* a    = (const float*)d_in[1];
    const float* Wx   = (const float*)d_in[2];
    const float* Wa   = (const float*)d_in[3];
    const float* g_qx = (const float*)d_in[4];
    const float* b_qx = (const float*)d_in[5];
    const float* g_kx = (const float*)d_in[6];
    const float* b_kx = (const float*)d_in[7];
    const float* g_qa = (const float*)d_in[8];
    const float* b_qa = (const float*)d_in[9];
    const float* g_ka = (const float*)d_in[10];
    const float* b_ka = (const float*)d_in[11];
    float* out = (float*)d_out;

    const size_t E = (size_t)BB*NH*SEQ*DH;   // 4M elements
    float* wsq = (float*)d_ws;               // 16MB
    float* wsk = wsq + E;                    // 16MB
    unsigned short* Qb = (unsigned short*)(wsk + E);  // 8MB
    unsigned short* Kb = Qb + E;                      // 8MB
    unsigned short* Vt = Kb + E;                      // 8MB

    qkv_gemm<<<dim3(MROWS/GBM, TD/GBN, 2), 256, 0, stream>>>(x, a, Wx, Wa, wsq, wsk, Vt);
    ln_rope<<<dim3(MROWS, 4), 512, 0, stream>>>(wsq, wsk, Qb, Kb,
        g_qx, b_qx, g_kx, b_kx, g_qa, b_qa, g_ka, b_ka);
    attn_mfma<<<dim3(SEQ/64, BB*NH), 256, 0, stream>>>(Qb, Kb, Vt, out);
}

// Round 3
// 128.444 us; speedup vs baseline: 4.9255x; 1.8250x over previous
//
#include <hip/hip_runtime.h>
#include <math.h>

typedef __attribute__((ext_vector_type(8))) short bf16x8;
typedef __attribute__((ext_vector_type(4))) short bf16x4;
typedef __attribute__((ext_vector_type(4))) float f32x4;

#define BB    4
#define SEQ   1024
#define DIMV  512
#define TD    1536
#define NH    8
#define DH    128
#define MROWS (BB*SEQ)

__device__ inline unsigned short f2bf(float x){
    union { float f; unsigned u; } v; v.f = x;
    unsigned r = v.u + 0x7FFF + ((v.u >> 16) & 1);   // RNE
    return (unsigned short)(r >> 16);
}
__device__ inline float bf2f(unsigned short h){
    union { unsigned u; float f; } v; v.u = ((unsigned)h) << 16; return v.f;
}

__device__ inline void glds16(const void* g, void* l){
    __builtin_amdgcn_global_load_lds(
        (const __attribute__((address_space(1))) unsigned int*)g,
        (__attribute__((address_space(3))) unsigned int*)l,
        16, 0, 0);
}

// ---------------- Prep A: split x|a into hi/lo bf16, K-granule-major ----------------
// Layout: Ahi[(mat*64 + p*4+g)*4096 + m][8] holds In[m][p*32+g*8 .. +7]
__global__ __launch_bounds__(256) void prep_a(
    const float* __restrict__ X, const float* __restrict__ A,
    unsigned short* __restrict__ Ahi, unsigned short* __restrict__ Alo)
{
    const int m   = blockIdx.x*256 + threadIdx.x;
    const int pg  = blockIdx.y;         // p*4+g  (0..63)
    const int mat = blockIdx.z;
    const float* In = mat ? A : X;
    const float* src = In + (size_t)m*DIMV + pg*8;
    float4 v0 = *(const float4*)src;
    float4 v1 = *(const float4*)(src+4);
    float v[8] = {v0.x,v0.y,v0.z,v0.w,v1.x,v1.y,v1.z,v1.w};
    bf16x8 h, l;
    #pragma unroll
    for (int j=0;j<8;++j){
        unsigned short hb = f2bf(v[j]);
        h[j] = (short)hb;
        l[j] = (short)f2bf(v[j] - bf2f(hb));
    }
    const size_t o = ((size_t)(mat*64 + pg)*4096 + m)*8;
    *(bf16x8*)(Ahi+o) = h;
    *(bf16x8*)(Alo+o) = l;
}

// ---------------- Prep B: transpose+split W into hi/lo bf16, K-granule-major ----------
// Layout: Bhi[(mat*64 + p*4+g)*1536 + n][8] holds W[p*32+g*8 .. +7][n]
__global__ __launch_bounds__(256) void prep_b(
    const float* __restrict__ Wx, const float* __restrict__ Wa,
    unsigned short* __restrict__ Bhi, unsigned short* __restrict__ Blo)
{
    const int n   = blockIdx.x*256 + threadIdx.x;
    const int pg  = blockIdx.y;
    const int mat = blockIdx.z;
    const float* W = mat ? Wa : Wx;
    bf16x8 h, l;
    #pragma unroll
    for (int j=0;j<8;++j){
        float v = W[(size_t)(pg*8 + j)*TD + n];
        unsigned short hb = f2bf(v);
        h[j] = (short)hb;
        l[j] = (short)f2bf(v - bf2f(hb));
    }
    const size_t o = ((size_t)(mat*64 + pg)*1536 + n)*8;
    *(bf16x8*)(Bhi+o) = h;
    *(bf16x8*)(Blo+o) = l;
}

// ---------------- Kernel 1: QKV GEMM via bf16 MFMA, hi/lo 3-pass ----------------
// 128x128 tile, BK=32, 4 waves (2x2 quadrants of 64x64). LDS 32KB.
__global__ __launch_bounds__(256,3) void qkv_mfma(
    const unsigned short* __restrict__ Ahi, const unsigned short* __restrict__ Alo,
    const unsigned short* __restrict__ Bhi, const unsigned short* __restrict__ Blo,
    float* __restrict__ wsq, float* __restrict__ wsk,
    unsigned short* __restrict__ Vt)
{
    __shared__ __align__(16) unsigned short sAh[4096];
    __shared__ __align__(16) unsigned short sAl[4096];
    __shared__ __align__(16) unsigned short sBh[4096];
    __shared__ __align__(16) unsigned short sBl[4096];

    const int mat = blockIdx.z;
    const int bm  = blockIdx.x * 128;
    const int bn  = blockIdx.y * 128;
    const int tid = threadIdx.x;
    const int w   = tid >> 6, l = tid & 63;
    const int wr  = w >> 1,  wc = w & 1;
    const int lg  = l >> 4,  ln = l & 15;

    f32x4 acc[4][4];
    #pragma unroll
    for (int i=0;i<4;++i)
        #pragma unroll
        for (int j=0;j<4;++j){ acc[i][j][0]=0.f; acc[i][j][1]=0.f; acc[i][j][2]=0.f; acc[i][j][3]=0.f; }

    // staging source pointers (chunk0: granules tid, chunk1: granules tid+256)
    const int g0 = tid >> 7, r0 = tid & 127;           // chunk0: g 0..1
    const size_t ASTEP = (size_t)4*4096*8;             // elements per K-panel
    const size_t BSTEP = (size_t)4*1536*8;
    const unsigned short* a0h = Ahi + ((size_t)(mat*64 + g0)*4096 + bm + r0)*8;
    const unsigned short* a0l = Alo + ((size_t)(mat*64 + g0)*4096 + bm + r0)*8;
    const unsigned short* a1h = a0h + (size_t)2*4096*8;   // chunk1: g+2
    const unsigned short* a1l = a0l + (size_t)2*4096*8;
    const unsigned short* b0h = Bhi + ((size_t)(mat*64 + g0)*1536 + bn + r0)*8;
    const unsigned short* b0l = Blo + ((size_t)(mat*64 + g0)*1536 + bn + r0)*8;
    const unsigned short* b1h = b0h + (size_t)2*1536*8;
    const unsigned short* b1l = b0l + (size_t)2*1536*8;

    // per-wave LDS dest bases (shorts): chunk0 = w*512, chunk1 = 2048 + w*512
    const int d0 = w*512, d1 = 2048 + w*512;

    for (int p=0; p<16; ++p){
        glds16(a0h, sAh + d0);  glds16(a1h, sAh + d1);
        glds16(a0l, sAl + d0);  glds16(a1l, sAl + d1);
        glds16(b0h, sBh + d0);  glds16(b1h, sBh + d1);
        glds16(b0l, sBl + d0);  glds16(b1l, sBl + d1);
        a0h += ASTEP; a1h += ASTEP; a0l += ASTEP; a1l += ASTEP;
        b0h += BSTEP; b1h += BSTEP; b0l += BSTEP; b1l += BSTEP;
        __syncthreads();   // drains vmcnt (global_load_lds) + lgkmcnt

        bf16x8 ah[4], al[4], bh[4], bl[4];
        #pragma unroll
        for (int mi=0; mi<4; ++mi){
            const int off = (lg*128 + wr*64 + mi*16 + ln)*8;
            ah[mi] = *(const bf16x8*)(sAh + off);
            al[mi] = *(const bf16x8*)(sAl + off);
        }
        #pragma unroll
        for (int ni=0; ni<4; ++ni){
            const int off = (lg*128 + wc*64 + ni*16 + ln)*8;
            bh[ni] = *(const bf16x8*)(sBh + off);
            bl[ni] = *(const bf16x8*)(sBl + off);
        }
        #pragma unroll
        for (int mi=0; mi<4; ++mi)
            #pragma unroll
            for (int ni=0; ni<4; ++ni){
                acc[mi][ni] = __builtin_amdgcn_mfma_f32_16x16x32_bf16(ah[mi], bh[ni], acc[mi][ni], 0,0,0);
                acc[mi][ni] = __builtin_amdgcn_mfma_f32_16x16x32_bf16(ah[mi], bl[ni], acc[mi][ni], 0,0,0);
                acc[mi][ni] = __builtin_amdgcn_mfma_f32_16x16x32_bf16(al[mi], bh[ni], acc[mi][ni], 0,0,0);
            }
        __syncthreads();
    }

    // ---- epilogue: scatter to q/k (f32 head layout) or V (bf16 transposed) ----
    const int b_ = bm >> 10;
    const int n0base = (bm & 1023) + wr*64;
    const int colB = bn + wc*64;
    if (colB < 1024){
        float* base = (colB < 512) ? wsq : wsk;
        #pragma unroll
        for (int ni=0; ni<4; ++ni){
            const int col = colB + ni*16 + ln;
            const int h = mat*4 + ((col >> 7) & 3);
            const int d = col & 127;
            #pragma unroll
            for (int mi=0; mi<4; ++mi){
                const int n0 = n0base + mi*16 + lg*4;
                float* dst = base + ((size_t)(b_*NH + h)*SEQ + n0)*DH + d;
                #pragma unroll
                for (int r=0;r<4;++r) dst[r*DH] = acc[mi][ni][r];
            }
        }
    } else {
        #pragma unroll
        for (int ni=0; ni<4; ++ni){
            const int col = colB + ni*16 + ln;
            const int h = mat*4 + ((col >> 7) & 3);
            const int d = col & 127;
            #pragma unroll
            for (int mi=0; mi<4; ++mi){
                const int n0 = n0base + mi*16 + lg*4;
                unsigned short* dst = Vt + ((size_t)(b_*NH + h)*DH + d)*SEQ + n0;
                bf16x4 pk;
                #pragma unroll
                for (int r=0;r<4;++r) pk[r] = (short)f2bf(acc[mi][ni][r]);
                *(bf16x4*)dst = pk;
            }
        }
    }
}

// ---------------- Kernel 2: LayerNorm + RoPE -> bf16 ----------------
__global__ __launch_bounds__(512) void ln_rope(
    const float* __restrict__ wsq, const float* __restrict__ wsk,
    unsigned short* __restrict__ Qb, unsigned short* __restrict__ Kb,
    const float* __restrict__ g_qx, const float* __restrict__ b_qx,
    const float* __restrict__ g_kx, const float* __restrict__ b_kx,
    const float* __restrict__ g_qa, const float* __restrict__ b_qa,
    const float* __restrict__ g_ka, const float* __restrict__ b_ka)
{
    __shared__ float red[16];
    __shared__ float vn[512];
    const int r = blockIdx.x;
    const int which = blockIdx.y;
    const int b_ = r >> 10;
    const int n_ = r & 1023;
    const float* buf = (which & 1) ? wsk : wsq;
    unsigned short* ob = (which & 1) ? Kb : Qb;
    const int h0 = (which >> 1) ? 4 : 0;
    const float* g; const float* bb;
    if (which==0){ g=g_qx; bb=b_qx; }
    else if (which==1){ g=g_kx; bb=b_kx; }
    else if (which==2){ g=g_qa; bb=b_qa; }
    else { g=g_ka; bb=b_ka; }

    const int t = threadIdx.x;
    const int h = h0 + (t >> 7);
    const int d = t & 127;
    const size_t idx = ((size_t)(b_*NH + h)*SEQ + n_)*DH + d;
    float v = buf[idx];
    float s1 = v, s2 = v*v;
    #pragma unroll
    for (int o=32;o>=1;o>>=1){
        s1 += __shfl_down(s1,o);
        s2 += __shfl_down(s2,o);
    }
    const int lane = t & 63, wv = t >> 6;
    if (lane==0){ red[wv]=s1; red[8+wv]=s2; }
    __syncthreads();
    float sum=0.f, sq=0.f;
    #pragma unroll
    for (int w=0;w<8;++w){ sum+=red[w]; sq+=red[8+w]; }
    const float mu = sum * (1.f/512.f);
    const float var = sq * (1.f/512.f) - mu*mu;
    const float rs = rsqrtf(var + 1e-5f);
    const float xn = (v - mu)*rs*g[t] + bb[t];
    vn[t] = xn;
    __syncthreads();
    const float partner = vn[t ^ 64];
    const int dd = d & 63;
    const float fr = (float)dd * (1.f/64.f);
    const float inv = expf(fr * -9.210340371976184f);
    const float ang = (float)n_ * inv;
    float sn, cs;
    sincosf(ang, &sn, &cs);
    const float rot = (d < 64) ? -partner : partner;
    float val = xn*cs + rot*sn;
    if (!(which & 1)) val *= 0.08838834764831845f;   // fold 1/sqrt(128) into Q
    ob[idx] = f2bf(val);
}

// ---------------- Kernel 3: MFMA flash attention (bf16) ----------------
__global__ __launch_bounds__(256) void attn_mfma(
    const unsigned short* __restrict__ Qb, const unsigned short* __restrict__ Kb,
    const unsigned short* __restrict__ Vt, float* __restrict__ out)
{
    __shared__ __align__(16) unsigned short Ks[64*128];   // 16KB, swizzled
    __shared__ __align__(16) unsigned short Vs[128*64];   // 16KB, V^T, swizzled
    __shared__ __align__(16) unsigned short Ps[4*16*64];  // 8KB, per-wave P

    const int bh = blockIdx.y;
    const int q0 = blockIdx.x * 64;
    const int tid = threadIdx.x;
    const int w  = tid >> 6;
    const int l  = tid & 63;
    const int lg = l >> 4;
    const int ln = l & 15;
    const size_t hoff = (size_t)bh * SEQ * DH;

    bf16x8 qf[4];
    {
        const unsigned short* qp = Qb + hoff + (size_t)(q0 + w*16 + ln)*DH + lg*8;
        #pragma unroll
        for (int c=0;c<4;++c) qf[c] = *(const bf16x8*)(qp + c*32);
    }

    f32x4 o[8];
    #pragma unroll
    for (int dt=0;dt<8;++dt){ o[dt][0]=0.f; o[dt][1]=0.f; o[dt][2]=0.f; o[dt][3]=0.f; }
    float mrun[4] = {-INFINITY,-INFINITY,-INFINITY,-INFINITY};
    float lrun[4] = {0.f,0.f,0.f,0.f};

    const unsigned short* kg0 = Kb + hoff;
    const unsigned short* vg0 = Vt + hoff;
    unsigned short* Pw = Ps + w*1024;
    const int lnsw = ln & 7;

    for (int kt=0; kt<SEQ/64; ++kt){
        __syncthreads();
        const unsigned short* kg = kg0 + (size_t)kt*64*DH;
        #pragma unroll
        for (int i=0;i<4;++i){
            int f = tid + i*256;
            int r = f >> 4, u = f & 15;
            *(bf16x8*)(Ks + r*128 + ((u ^ (r&7))*8)) = *(const bf16x8*)(kg + r*128 + u*8);
        }
        #pragma unroll
        for (int i=0;i<4;++i){
            int f = tid + i*256;
            int dr = f >> 3, u = f & 7;
            *(bf16x8*)(Vs + dr*64 + ((u ^ (dr&7))*8)) =
                *(const bf16x8*)(vg0 + (size_t)dr*SEQ + kt*64 + u*8);
        }
        __syncthreads();

        f32x4 s[4];
        #pragma unroll
        for (int ct=0;ct<4;++ct){ s[ct][0]=0.f; s[ct][1]=0.f; s[ct][2]=0.f; s[ct][3]=0.f; }
        #pragma unroll
        for (int ct=0; ct<4; ++ct){
            const int kr = ct*16 + ln;
            const unsigned short* kb = Ks + kr*128;
            const int sw = kr & 7;
            #pragma unroll
            for (int c=0;c<4;++c){
                bf16x8 kf = *(const bf16x8*)(kb + ((((c<<2)|lg) ^ sw)*8));
                s[ct] = __builtin_amdgcn_mfma_f32_16x16x32_bf16(qf[c], kf, s[ct], 0,0,0);
            }
        }

        float pv[4][4];
        float al[4];
        #pragma unroll
        for (int r=0;r<4;++r){
            float mx = fmaxf(fmaxf(s[0][r], s[1][r]), fmaxf(s[2][r], s[3][r]));
            mx = fmaxf(mx, __shfl_xor(mx,1));
            mx = fmaxf(mx, __shfl_xor(mx,2));
            mx = fmaxf(mx, __shfl_xor(mx,4));
            mx = fmaxf(mx, __shfl_xor(mx,8));
            const float mn = fmaxf(mrun[r], mx);
            const float a  = __expf(mrun[r]-mn);
            float sum = 0.f;
            #pragma unroll
            for (int ct=0;ct<4;++ct){
                float p = __expf(s[ct][r]-mn);
                pv[r][ct] = p; sum += p;
            }
            sum += __shfl_xor(sum,1);
            sum += __shfl_xor(sum,2);
            sum += __shfl_xor(sum,4);
            sum += __shfl_xor(sum,8);
            lrun[r] = lrun[r]*a + sum;
            mrun[r] = mn;
            al[r] = a;
        }

        #pragma unroll
        for (int dt=0;dt<8;++dt){
            o[dt][0]*=al[0]; o[dt][1]*=al[1]; o[dt][2]*=al[2]; o[dt][3]*=al[3];
        }

        #pragma unroll
        for (int r=0;r<4;++r){
            const int m = lg*4 + r;
            unsigned short* pr = Pw + m*64;
            const int sw = m & 7;
            #pragma unroll
            for (int ct=0;ct<4;++ct){
                int col = ct*16 + ln;
                pr[(((col>>3) ^ sw)*8) + (col&7)] = f2bf(pv[r][ct]);
            }
        }

        #pragma unroll
        for (int kc=0;kc<2;++kc){
            bf16x8 pf = *(const bf16x8*)(Pw + ln*64 + ((((kc<<2)|lg) ^ lnsw)*8));
            #pragma unroll
            for (int dt=0;dt<8;++dt){
                const int vr = dt*16 + ln;
                bf16x8 vf = *(const bf16x8*)(Vs + vr*64 + ((((kc<<2)|lg) ^ lnsw)*8));
                o[dt] = __builtin_amdgcn_mfma_f32_16x16x32_bf16(pf, vf, o[dt], 0,0,0);
            }
        }
    }

    const int b_ = bh >> 3, h_ = bh & 7;
    #pragma unroll
    for (int r=0;r<4;++r){
        const float inv = 1.0f / lrun[r];
        const int n_ = q0 + w*16 + lg*4 + r;
        float* op = out + ((size_t)(b_*SEQ) + n_)*1024 + h_*128 + ln;
        #pragma unroll
        for (int dt=0;dt<8;++dt)
            op[dt*16] = o[dt][r] * inv;
    }
}

extern "C" void kernel_launch(void* const* d_in, const int* in_sizes, int n_in,
                              void* d_out, int out_size, void* d_ws, size_t ws_size,
                              hipStream_t stream) {
    const float* x    = (const float*)d_in[0];
    const float* a    = (const float*)d_in[1];
    const float* Wx   = (const float*)d_in[2];
    const float* Wa   = (const float*)d_in[3];
    const float* g_qx = (const float*)d_in[4];
    const float* b_qx = (const float*)d_in[5];
    const float* g_kx = (const float*)d_in[6];
    const float* b_kx = (const float*)d_in[7];
    const float* g_qa = (const float*)d_in[8];
    const float* b_qa = (const float*)d_in[9];
    const float* g_ka = (const float*)d_in[10];
    const float* b_ka = (const float*)d_in[11];
    float* out = (float*)d_out;

    const size_t E = (size_t)BB*NH*SEQ*DH;        // 4,194,304 elements
    float* wsq = (float*)d_ws;                    // 16MB
    float* wsk = wsq + E;                         // 16MB
    unsigned short* Vt = (unsigned short*)(wsk + E);  // 8MB
    unsigned short* region = Vt + E;              // 16MB, dual-use
    unsigned short* Ahi = region;                 // 8MB (gemm phase)
    unsigned short* Alo = region + E;             // 8MB
    unsigned short* Qb  = region;                 // 8MB (attn phase)
    unsigned short* Kb  = region + E;             // 8MB
    unsigned short* Bhi = region + 2*E;           // 3MB
    unsigned short* Blo = Bhi + (size_t)2*64*1536*8;  // 3MB

    prep_a<<<dim3(16, 64, 2), 256, 0, stream>>>(x, a, Ahi, Alo);
    prep_b<<<dim3(6, 64, 2), 256, 0, stream>>>(Wx, Wa, Bhi, Blo);
    qkv_mfma<<<dim3(32, 12, 2), 256, 0, stream>>>(Ahi, Alo, Bhi, Blo, wsq, wsk, Vt);
    ln_rope<<<dim3(MROWS, 4), 512, 0, stream>>>(wsq, wsk, Qb, Kb,
        g_qx, b_qx, g_kx, b_kx, g_qa, b_qa, g_ka, b_ka);
    attn_mfma<<<dim3(SEQ/64, BB*NH), 256, 0, stream>>>(Qb, Kb, Vt, out);
}